// Round 8
// baseline (225.836 us; speedup 1.0000x reference)
//
#include <hip/hip_runtime.h>

#define BB 32
#define SS 512
#define LL 64
#define TSTART 61
#define TSTOP 62
#define NSEG 32
#define SEGLEN 16
#define QPAD 68

typedef short short8 __attribute__((ext_vector_type(8)));
typedef float floatx4 __attribute__((ext_vector_type(4)));

union S8 { int i[4]; uint4 u4; short8 v; };

// half-up bf16 round + pack (positive values only): 4 VALU ops
__device__ inline int pack_bf16(float a, float b) {
    unsigned ua = __float_as_uint(a) + 0x8000u;
    unsigned ub = __float_as_uint(b) + 0x8000u;
    return (int)((ua >> 16) | (ub & 0xffff0000u));
}

// ---------------- combine (device fn): MFMA fold of a0 through active segments ----
// One wave. A = P_s^T (bf16 from ws, double-banked 2 folds ahead); B = alpha
// broadcast into all 16 cols (result replicated per col).
__device__ void combine_batch(int b, int j, const float* __restrict__ enc,
                              const float* __restrict__ Tr, int len,
                              const unsigned short* __restrict__ wsQ,
                              const float* __restrict__ wsS,
                              float* __restrict__ Al,
                              float* __restrict__ out)
{
    const int smax = (len - 2) / SEGLEN + 1;   // active segments (len >= 2)
    const int q = j >> 4;
    const int lcol = j & 15;

    const uint4* qb = (const uint4*)(wsQ + (size_t)b * NSEG * 4096);
    int fidx[4][2];
    #pragma unroll
    for (int mt = 0; mt < 4; ++mt)
        #pragma unroll
        for (int c2 = 0; c2 < 2; ++c2)
            fidx[mt][c2] = (16 * mt + lcol) * 8 + 4 * c2 + q;

    float sc0 = wsS[b * (NSEG * 4) + j];      // per-unit log scales (4s+g -> lane)
    float sc1 = wsS[b * (NSEG * 4) + 64 + j];

    float alpha0 = Tr[TSTART * LL + j] + enc[b * (SS * LL) + j];
    float m = alpha0;
    #pragma unroll
    for (int off = 32; off; off >>= 1) m = fmaxf(m, __shfl_xor(m, off));
    Al[j] = __expf(alpha0 - m);
    float logscale = m;
    float invmx = 1.0f;

    uint4 Abuf0[8], Abuf1[8];
    {
        const uint4* p1 = qb + (size_t)min(1, smax - 1) * 512;
        #pragma unroll
        for (int mt = 0; mt < 4; ++mt)
            #pragma unroll
            for (int c2 = 0; c2 < 2; ++c2) {
                Abuf0[mt * 2 + c2] = qb[fidx[mt][c2]];
                Abuf1[mt * 2 + c2] = p1[fidx[mt][c2]];
            }
    }

    int s = 0;
    auto fold = [&](uint4 (&cur)[8]) {
        float4 q0 = *(const float4*)(Al + 8 * q);
        float4 q1 = *(const float4*)(Al + 8 * q + 4);
        float4 q2 = *(const float4*)(Al + 32 + 8 * q);
        float4 q3 = *(const float4*)(Al + 32 + 8 * q + 4);
        S8 b0, b1;
        b0.i[0] = pack_bf16(q0.x * invmx, q0.y * invmx);
        b0.i[1] = pack_bf16(q0.z * invmx, q0.w * invmx);
        b0.i[2] = pack_bf16(q1.x * invmx, q1.y * invmx);
        b0.i[3] = pack_bf16(q1.z * invmx, q1.w * invmx);
        b1.i[0] = pack_bf16(q2.x * invmx, q2.y * invmx);
        b1.i[1] = pack_bf16(q2.z * invmx, q2.w * invmx);
        b1.i[2] = pack_bf16(q3.x * invmx, q3.y * invmx);
        b1.i[3] = pack_bf16(q3.z * invmx, q3.w * invmx);

        S8 a8[8];
        #pragma unroll
        for (int f = 0; f < 8; ++f) a8[f].u4 = cur[f];

        const uint4* pn = qb + (size_t)min(s + 2, smax - 1) * 512;
        #pragma unroll
        for (int mt = 0; mt < 4; ++mt)
            #pragma unroll
            for (int c2 = 0; c2 < 2; ++c2) cur[mt * 2 + c2] = pn[fidx[mt][c2]];

        floatx4 acc[4];
        #pragma unroll
        for (int mt = 0; mt < 4; ++mt) {
            floatx4 z = {0.f, 0.f, 0.f, 0.f};
            z = __builtin_amdgcn_mfma_f32_16x16x32_bf16(a8[2 * mt].v, b0.v, z, 0, 0, 0);
            z = __builtin_amdgcn_mfma_f32_16x16x32_bf16(a8[2 * mt + 1].v, b1.v, z, 0, 0, 0);
            acc[mt] = z;
        }

        float l0, l1, l2, l3;
        if (s < 16) {
            l0 = __shfl(sc0, 4 * s + 0); l1 = __shfl(sc0, 4 * s + 1);
            l2 = __shfl(sc0, 4 * s + 2); l3 = __shfl(sc0, 4 * s + 3);
        } else {
            int e = 4 * (s - 16);
            l0 = __shfl(sc1, e + 0); l1 = __shfl(sc1, e + 1);
            l2 = __shfl(sc1, e + 2); l3 = __shfl(sc1, e + 3);
        }
        float lmax = fmaxf(fmaxf(l0, l1), fmaxf(l2, l3));
        float e0 = __expf(l0 - lmax), e1 = __expf(l1 - lmax);
        float e2 = __expf(l2 - lmax), e3 = __expf(l3 - lmax);
        #pragma unroll
        for (int r = 0; r < 4; ++r) {
            acc[0][r] *= e0; acc[1][r] *= e1; acc[2][r] *= e2; acc[3][r] *= e3;
        }

        if (lcol == 0) {
            #pragma unroll
            for (int mt = 0; mt < 4; ++mt)
                *(float4*)(Al + 16 * mt + 4 * q) =
                    make_float4(acc[mt][0], acc[mt][1], acc[mt][2], acc[mt][3]);
        }

        float mx = acc[0][0];
        #pragma unroll
        for (int mt = 0; mt < 4; ++mt)
            #pragma unroll
            for (int r = 0; r < 4; ++r) mx = fmaxf(mx, acc[mt][r]);
        mx = fmaxf(mx, __shfl_xor(mx, 16));
        mx = fmaxf(mx, __shfl_xor(mx, 32));
        invmx = 1.0f / mx;
        logscale += lmax + __logf(mx);
    };

    while (s < smax) {
        fold(Abuf0);
        ++s;
        if (s >= smax) break;
        fold(Abuf1);
        ++s;
    }

    float aj = Al[j] * invmx;
    float f = aj * __expf(Tr[j * LL + TSTOP]);
    float ssum = f;
    #pragma unroll
    for (int off = 32; off; off >>= 1) ssum += __shfl_xor(ssum, off);
    if (j == 0) {
        const float LN2x7 = 7.0f * 0.69314718055994530942f;
        out[b] = logscale + (float)(len - 1) * LN2x7 + __logf(ssum);
    }
}

// ---------------- fused kernel ----------------
// Blocks 0..4095 (one wave): segment product for unit=blk (b=blk>>7,
//   s=(blk>>2)&31, g=blk&3); ALL 128 units of a batch then hit the batch's
//   atomicInc; the unique 128th arriver (old==126; works off 0xAA poison,
//   no memset node) runs the MFMA combine for that batch.
// Blocks 4096..4127: labeled path for batch blk-4096 (one wave).
__global__ __launch_bounds__(64, 4) void crf_fused_kernel(
    const float* __restrict__ enc, const float* __restrict__ Tr,
    const int* __restrict__ lens, const int* __restrict__ tags,
    unsigned short* __restrict__ wsQ, float* __restrict__ wsS,
    unsigned int* __restrict__ cnt,
    float* __restrict__ out)
{
    const int blk = blockIdx.x;
    const int lane = threadIdx.x;

    if (blk >= BB * NSEG * 4) {
        // ---------------- labeled path (one wave) ----------------
        const int b = blk - BB * NSEG * 4;
        const int len = lens[b];
        const int* tg = tags + b * SS;
        const float* eb = enc + b * (SS * LL);
        float acc = 0.f;
        for (int t = 1 + lane; t < len; t += 64) {
            int curt = tg[t], prevt = tg[t - 1];
            acc += Tr[prevt * LL + curt] + eb[t * LL + curt];
        }
        #pragma unroll
        for (int off = 32; off; off >>= 1) acc += __shfl_xor(acc, off);
        if (lane == 0) {
            int t0 = tg[0], te = tg[len - 1];
            acc += Tr[TSTART * LL + t0] + eb[t0];
            acc += Tr[te * LL + TSTOP];
            out[BB + b] = acc;
        }
        return;
    }

    const int b = blk >> 7;
    const int s = (blk >> 2) & 31;
    const int g = blk & 3;
    const int len = lens[b];
    const int tlo = SEGLEN * s + 1;
    const int Teff = min(len - tlo, SEGLEN);

    __shared__ __align__(16) float QT[16 * QPAD];   // running product [col][row]
    __shared__ __align__(16) float W16[16 * 64];    // staged w vectors [tt][row]
    __shared__ __align__(16) float Al[64];          // combine alpha buffer

    if (Teff > 0) {                         // active unit: compute P_seg
        const int q = lane >> 4;
        const int lcol = lane & 15;
        const float* eb = enc + b * (SS * LL);

        // encoder rows for this segment (coalesced, issued early)
        float ev[16];
        #pragma unroll
        for (int k = 0; k < 16; ++k) ev[k] = eb[min(tlo + k, SS - 1) * LL + lane];

        // A operand: A[m][k] = E^T[m][k] = exp(T[k][m]) * 2^-7 (bf16)
        short8 Afr[4][2];
        #pragma unroll
        for (int mt = 0; mt < 4; ++mt)
            #pragma unroll
            for (int c2 = 0; c2 < 2; ++c2) {
                float av[8];
                #pragma unroll
                for (int idx = 0; idx < 8; ++idx) {
                    int kk = 32 * c2 + 8 * q + idx;
                    int mm = 16 * mt + lcol;
                    av[idx] = __expf(Tr[kk * LL + mm]) * 0.0078125f;
                }
                S8 u;
                #pragma unroll
                for (int w2 = 0; w2 < 4; ++w2) u.i[w2] = pack_bf16(av[2 * w2], av[2 * w2 + 1]);
                Afr[mt][c2] = u.v;
            }

        // QT init: column 16g+lcol of E^T
        {
            const float* trow = Tr + (16 * g + lcol) * LL;
            #pragma unroll
            for (int u = 0; u < 4; ++u) {
                float4 tv = *(const float4*)(trow + 16 * q + 4 * u);
                float4 evv;
                evv.x = __expf(tv.x) * 0.0078125f;
                evv.y = __expf(tv.y) * 0.0078125f;
                evv.z = __expf(tv.z) * 0.0078125f;
                evv.w = __expf(tv.w) * 0.0078125f;
                *(float4*)(QT + lcol * QPAD + 16 * q + 4 * u) = evv;
            }
        }

        // stage all 16 w rows up front (off the MFMA chain)
        #pragma unroll
        for (int k = 0; k < 16; ++k) W16[k * 64 + lane] = __expf(ev[k]);

        float lg = 0.0f;
        #pragma unroll
        for (int cc = 0; cc < 2; ++cc) {
            #pragma unroll
            for (int k = 0; k < 8; ++k) {
                const int i = 8 * cc + k + 2;         // step index 2..17
                if (i <= Teff) {                      // wave-uniform
                    const int wloc = 8 * cc + k;      // uses w_{tlo+i-2}
                    float4 qv[2][2], wv[2][2];
                    #pragma unroll
                    for (int c2 = 0; c2 < 2; ++c2)
                        #pragma unroll
                        for (int h = 0; h < 2; ++h) {
                            qv[c2][h] = *(const float4*)(QT + lcol * QPAD + 32 * c2 + 8 * q + 4 * h);
                            wv[c2][h] = *(const float4*)(W16 + wloc * 64 + 32 * c2 + 8 * q + 4 * h);
                        }
                    short8 Bfr[2];
                    #pragma unroll
                    for (int c2 = 0; c2 < 2; ++c2) {
                        S8 u;
                        u.i[0] = pack_bf16(qv[c2][0].x * wv[c2][0].x, qv[c2][0].y * wv[c2][0].y);
                        u.i[1] = pack_bf16(qv[c2][0].z * wv[c2][0].z, qv[c2][0].w * wv[c2][0].w);
                        u.i[2] = pack_bf16(qv[c2][1].x * wv[c2][1].x, qv[c2][1].y * wv[c2][1].y);
                        u.i[3] = pack_bf16(qv[c2][1].z * wv[c2][1].z, qv[c2][1].w * wv[c2][1].w);
                        Bfr[c2] = u.v;
                    }
                    float ov[4][4];
                    #pragma unroll
                    for (int mt = 0; mt < 4; ++mt) {
                        floatx4 z = {0.f, 0.f, 0.f, 0.f};
                        z = __builtin_amdgcn_mfma_f32_16x16x32_bf16(Afr[mt][0], Bfr[0], z, 0, 0, 0);
                        z = __builtin_amdgcn_mfma_f32_16x16x32_bf16(Afr[mt][1], Bfr[1], z, 0, 0, 0);
                        ov[mt][0] = z[0]; ov[mt][1] = z[1]; ov[mt][2] = z[2]; ov[mt][3] = z[3];
                    }
                    if (cc == 0 && k == 7) {          // single mid-chain rescale (i=9)
                        float mx = ov[0][0];
                        #pragma unroll
                        for (int mt = 0; mt < 4; ++mt)
                            #pragma unroll
                            for (int r = 0; r < 4; ++r) mx = fmaxf(mx, ov[mt][r]);
                        #pragma unroll
                        for (int off = 32; off; off >>= 1) mx = fmaxf(mx, __shfl_xor(mx, off));
                        lg += __logf(mx);
                        float rmx = 1.0f / mx;
                        #pragma unroll
                        for (int mt = 0; mt < 4; ++mt)
                            #pragma unroll
                            for (int r = 0; r < 4; ++r) ov[mt][r] *= rmx;
                    }
                    #pragma unroll
                    for (int mt = 0; mt < 4; ++mt) {
                        float4 sv = make_float4(ov[mt][0], ov[mt][1], ov[mt][2], ov[mt][3]);
                        *(float4*)(QT + lcol * QPAD + 16 * mt + 4 * q) = sv;
                    }
                }
            }
        }

        // final row scale by w_last; write P^T as BF16 [col][row]
        const float* wl = W16 + (Teff - 1) * 64;
        unsigned short* qdst = wsQ + (size_t)(b * NSEG + s) * 4096 + (16 * g + lcol) * 64;
        #pragma unroll
        for (int u = 0; u < 2; ++u) {
            const int r0 = 16 * q + 8 * u;
            float4 m0 = *(const float4*)(QT + lcol * QPAD + r0);
            float4 m1 = *(const float4*)(QT + lcol * QPAD + r0 + 4);
            float4 w0 = *(const float4*)(wl + r0);
            float4 w1 = *(const float4*)(wl + r0 + 4);
            S8 o;
            o.i[0] = pack_bf16(m0.x * w0.x, m0.y * w0.y);
            o.i[1] = pack_bf16(m0.z * w0.z, m0.w * w0.w);
            o.i[2] = pack_bf16(m1.x * w1.x, m1.y * w1.y);
            o.i[3] = pack_bf16(m1.z * w1.z, m1.w * w1.w);
            *(uint4*)(qdst + r0) = o.u4;
        }
        if (lane == 0) wsS[(b * NSEG + s) * 4 + g] = lg;
    }

    // -------- unique 128th arriver of this batch runs the combine --------
    __threadfence();                         // release: P^T + wsS visible device-wide
    unsigned int old = 0;
    if (lane == 0) old = atomicInc(&cnt[b], 127u);  // poison>=127 -> first arrival resets to 0
    old = __shfl((int)old, 0);
    if (old == 126u) {
        __threadfence();                     // acquire: see all units' writes
        combine_batch(b, lane, enc, Tr, len, wsQ, wsS, Al, out);
    }
}

// ---------------- Fallback (exact, used if ws too small) ----------------
__global__ __launch_bounds__(256) void crf_kernel_fb(
    const float* __restrict__ enc, const float* __restrict__ Tr,
    const int* __restrict__ lens, const int* __restrict__ tags,
    float* __restrict__ out)
{
    if (blockIdx.x < BB) {
        const int tid = threadIdx.x;
        if (tid >= 64) return;
        const int b = blockIdx.x;
        const int j = tid;
        const int len = lens[b];
        const float* eb = enc + b * (SS * LL);
        float Ecol[LL];
        #pragma unroll
        for (int i = 0; i < LL; ++i) Ecol[i] = __expf(Tr[i * LL + j]) * 0.0078125f;
        float alpha0 = Tr[TSTART * LL + j] + eb[j];
        float m = alpha0;
        #pragma unroll
        for (int off = 32; off; off >>= 1) m = fmaxf(m, __shfl_xor(m, off));
        float a = __expf(alpha0 - m);
        float logscale = m;
        float ecur[4], enext[4];
        #pragma unroll
        for (int k = 0; k < 4; ++k) ecur[k] = eb[k * LL + j];
        #pragma unroll
        for (int k = 0; k < 4; ++k) enext[k] = eb[(4 + k) * LL + j];
        const int nchunk = (len + 3) >> 2;
        for (int c = 0; c < nchunk; ++c) {
            const int cpre = (c + 2 < 128) ? (c + 2) : 127;
            float efar[4];
            #pragma unroll
            for (int k = 0; k < 4; ++k) efar[k] = eb[(4 * cpre + k) * LL + j];
            #pragma unroll
            for (int k = 0; k < 4; ++k) {
                const int t = 4 * c + k;
                if (t >= 1 && t < len) {
                    const float w = __expf(ecur[k]);
                    const int ai = __float_as_int(a);
                    float s0 = 0.f, s1 = 0.f, s2 = 0.f, s3 = 0.f;
                    #pragma unroll
                    for (int qq = 0; qq < 16; ++qq) {
                        s0 = fmaf(__int_as_float(__builtin_amdgcn_readlane(ai, 4 * qq + 0)), Ecol[4 * qq + 0], s0);
                        s1 = fmaf(__int_as_float(__builtin_amdgcn_readlane(ai, 4 * qq + 1)), Ecol[4 * qq + 1], s1);
                        s2 = fmaf(__int_as_float(__builtin_amdgcn_readlane(ai, 4 * qq + 2)), Ecol[4 * qq + 2], s2);
                        s3 = fmaf(__int_as_float(__builtin_amdgcn_readlane(ai, 4 * qq + 3)), Ecol[4 * qq + 3], s3);
                    }
                    a = ((s0 + s1) + (s2 + s3)) * w;
                    if ((t & 7) == 7) {
                        float mm = a;
                        #pragma unroll
                        for (int off = 32; off; off >>= 1) mm = fmaxf(mm, __shfl_xor(mm, off));
                        logscale += __logf(mm);
                        a = a * (1.0f / mm);
                    }
                }
            }
            #pragma unroll
            for (int k = 0; k < 4; ++k) { ecur[k] = enext[k]; enext[k] = efar[k]; }
        }
        float f = a * __expf(Tr[j * LL + TSTOP]);
        float ssum = f;
        #pragma unroll
        for (int off = 32; off; off >>= 1) ssum += __shfl_xor(ssum, off);
        if (j == 0) {
            const float LN2x7 = 7.0f * 0.69314718055994530942f;
            out[b] = logscale + (float)(len - 1) * LN2x7 + __logf(ssum);
        }
    } else {
        const int b = blockIdx.x - BB;
        const int tid = threadIdx.x;
        const int len = lens[b];
        const int* tg = tags + b * SS;
        const float* eb = enc + b * (SS * LL);
        float acc = 0.f;
        for (int t = 1 + tid; t < len; t += 256) {
            int curt = tg[t], prevt = tg[t - 1];
            acc += Tr[prevt * LL + curt] + eb[t * LL + curt];
        }
        #pragma unroll
        for (int off = 32; off; off >>= 1) acc += __shfl_xor(acc, off);
        __shared__ float red[4];
        if ((tid & 63) == 0) red[tid >> 6] = acc;
        __syncthreads();
        if (tid == 0) {
            float tot = (red[0] + red[1]) + (red[2] + red[3]);
            int t0 = tg[0], te = tg[len - 1];
            tot += Tr[TSTART * LL + t0] + eb[t0];
            tot += Tr[te * LL + TSTOP];
            out[BB + b] = tot;
        }
    }
}

extern "C" void kernel_launch(void* const* d_in, const int* in_sizes, int n_in,
                              void* d_out, int out_size, void* d_ws, size_t ws_size,
                              hipStream_t stream) {
    const float* enc  = (const float*)d_in[0];
    const float* Tr   = (const float*)d_in[1];
    const int*   lens = (const int*)d_in[2];
    const int*   tags = (const int*)d_in[3];
    float* out = (float*)d_out;

    const size_t needQ = (size_t)BB * NSEG * 4096 * sizeof(unsigned short);  // 8 MB
    const size_t needS = (size_t)BB * NSEG * 4 * sizeof(float);              // 16 KB
    const size_t needC = (size_t)BB * sizeof(unsigned int);
    if (ws_size >= needQ + needS + needC) {
        unsigned short* wsQ = (unsigned short*)d_ws;
        float* wsS = (float*)((char*)d_ws + needQ);
        unsigned int* cnt = (unsigned int*)((char*)d_ws + needQ + needS);
        crf_fused_kernel<<<BB * NSEG * 4 + BB, 64, 0, stream>>>(
            enc, Tr, lens, tags, wsQ, wsS, cnt, out);
    } else {
        crf_kernel_fb<<<2 * BB, 256, 0, stream>>>(enc, Tr, lens, tags, out);
    }
}

// Round 9
// 102.077 us; speedup vs baseline: 2.2124x; 2.2124x over previous
//
#include <hip/hip_runtime.h>

#define BB 32
#define SS 512
#define LL 64
#define TSTART 61
#define TSTOP 62
#define NSEG 32
#define SEGLEN 16
#define QPADB 72   // bf16 QT row stride

typedef short short8 __attribute__((ext_vector_type(8)));
typedef float floatx4 __attribute__((ext_vector_type(4)));

union S8 { int i[4]; uint4 u4; short8 v; };

// half-up bf16 round + pack (positive values only)
__device__ inline int pack_bf16(float a, float b) {
    unsigned ua = __float_as_uint(a) + 0x8000u;
    unsigned ub = __float_as_uint(b) + 0x8000u;
    return (int)((ua >> 16) | (ub & 0xffff0000u));
}

// ---------------- Kernel 0: labeled path + E-table prep ----------------
// Blocks 0..31: labeled path for batch b (one wave).
// Block 32: build tblE[c*64+r] = exp(T[c][r])*2^-7 (f32) and tblA, the
//   MFMA A-fragment table: tblA[(mt*2+c2)*64 + lane] = packed bf16
//   {E^T[16mt+lcol][32c2+8q+idx], idx 0..7} for lane=(q,lcol).
__global__ __launch_bounds__(64) void crf_prep_kernel(
    const float* __restrict__ enc, const float* __restrict__ Tr,
    const int* __restrict__ lens, const int* __restrict__ tags,
    uint4* __restrict__ tblA, float* __restrict__ tblE,
    float* __restrict__ out)
{
    const int blk = blockIdx.x;
    const int lane = threadIdx.x;
    if (blk < BB) {
        const int b = blk;
        const int len = lens[b];
        const int* tg = tags + b * SS;
        const float* eb = enc + b * (SS * LL);
        float acc = 0.f;
        for (int t = 1 + lane; t < len; t += 64) {
            int curt = tg[t], prevt = tg[t - 1];
            acc += Tr[prevt * LL + curt] + eb[t * LL + curt];
        }
        #pragma unroll
        for (int off = 32; off; off >>= 1) acc += __shfl_xor(acc, off);
        if (lane == 0) {
            int t0 = tg[0], te = tg[len - 1];
            acc += Tr[TSTART * LL + t0] + eb[t0];
            acc += Tr[te * LL + TSTOP];
            out[BB + b] = acc;
        }
        return;
    }
    // block 32: lane = m (row of E^T)
    float rv[64];
    #pragma unroll
    for (int k = 0; k < 64; ++k) {
        float v = __expf(Tr[k * LL + lane]) * 0.0078125f;  // exp(T[k][lane])
        rv[k] = v;
        tblE[k * LL + lane] = v;                           // tblE[c=k][r=lane]
    }
    const int mt = lane >> 4, lc = lane & 15;
    #pragma unroll
    for (int c2 = 0; c2 < 2; ++c2)
        #pragma unroll
        for (int q = 0; q < 4; ++q) {
            int k0 = 32 * c2 + 8 * q;
            uint4 u;
            u.x = (unsigned)pack_bf16(rv[k0 + 0], rv[k0 + 1]);
            u.y = (unsigned)pack_bf16(rv[k0 + 2], rv[k0 + 3]);
            u.z = (unsigned)pack_bf16(rv[k0 + 4], rv[k0 + 5]);
            u.w = (unsigned)pack_bf16(rv[k0 + 6], rv[k0 + 7]);
            tblA[(mt * 2 + c2) * 64 + q * 16 + lc] = u;
        }
}

// ---------------- Kernel 1: segment transfer-matrix products ----------------
// 4096 one-wave blocks: b=blk>>7, s=(blk>>2)&31, g=blk&3.
//   QT (LDS, bf16, [col][row]) holds the running product PRE-SCALED by the
//   current w — stored bytes ARE the next MFMA B fragment. A frags from tblA
//   (8 coalesced uint4 loads). Per step: 2 b128 B-reads + 8 MFMA + 4 b128
//   w-reads (C-layout) + 16 mul + 8 pack + 4 b64 writes.
__global__ __launch_bounds__(64, 4) void crf_seg_kernel(
    const float* __restrict__ enc, const int* __restrict__ lens,
    const uint4* __restrict__ tblA, const float* __restrict__ tblE,
    unsigned short* __restrict__ wsQ, float* __restrict__ wsS)
{
    const int blk = blockIdx.x;
    const int lane = threadIdx.x;
    const int b = blk >> 7;
    const int s = (blk >> 2) & 31;
    const int g = blk & 3;
    const int len = lens[b];
    const int tlo = SEGLEN * s + 1;
    const int Teff = min(len - tlo, SEGLEN);
    if (Teff <= 0) return;                 // combine skips s >= smax

    const int q = lane >> 4;
    const int lcol = lane & 15;
    const float* eb = enc + b * (SS * LL);

    __shared__ __align__(16) unsigned short QT[16 * QPADB];  // bf16 product [col][row]
    __shared__ __align__(16) float W16[16 * 64];             // w vectors [tt][row]

    // issue all independent loads first
    float ev[16];
    if (Teff == SEGLEN) {
        #pragma unroll
        for (int k = 0; k < 16; ++k) ev[k] = eb[(tlo + k) * LL + lane];
    } else {
        #pragma unroll
        for (int k = 0; k < 16; ++k) ev[k] = eb[min(tlo + k, SS - 1) * LL + lane];
    }
    S8 Af[8];
    #pragma unroll
    for (int f = 0; f < 8; ++f) Af[f].u4 = tblA[f * 64 + lane];
    float4 ei[4];
    #pragma unroll
    for (int u = 0; u < 4; ++u)
        ei[u] = *(const float4*)(tblE + (16 * g + lcol) * LL + 16 * q + 4 * u);

    // stage w rows
    #pragma unroll
    for (int k = 0; k < 16; ++k) W16[k * 64 + lane] = __expf(ev[k]);

    // QT init = D(w_tlo) * E^T, bf16: lane covers rows 16q..16q+15 of col lcol
    {
        int p[8];
        #pragma unroll
        for (int u = 0; u < 4; ++u) {
            float4 wv = *(const float4*)(W16 + 16 * q + 4 * u);   // w_tlo rows
            p[2 * u]     = pack_bf16(ei[u].x * wv.x, ei[u].y * wv.y);
            p[2 * u + 1] = pack_bf16(ei[u].z * wv.z, ei[u].w * wv.w);
        }
        unsigned short* qt = QT + lcol * QPADB + 16 * q;
        *(uint4*)(qt)     = make_uint4(p[0], p[1], p[2], p[3]);
        *(uint4*)(qt + 8) = make_uint4(p[4], p[5], p[6], p[7]);
    }

    float lg = 0.0f;
    #pragma unroll
    for (int cc = 0; cc < 2; ++cc) {
        #pragma unroll
        for (int k = 0; k < 8; ++k) {
            const int i = 8 * cc + k + 2;         // step index 2..17
            if (i <= Teff) {                      // wave-uniform
                S8 B0, B1;
                B0.u4 = *(const uint4*)(QT + lcol * QPADB + 8 * q);
                B1.u4 = *(const uint4*)(QT + lcol * QPADB + 32 + 8 * q);
                floatx4 z[4];
                #pragma unroll
                for (int mt = 0; mt < 4; ++mt) {
                    floatx4 zz = {0.f, 0.f, 0.f, 0.f};
                    zz = __builtin_amdgcn_mfma_f32_16x16x32_bf16(Af[2 * mt].v,     B0.v, zz, 0, 0, 0);
                    zz = __builtin_amdgcn_mfma_f32_16x16x32_bf16(Af[2 * mt + 1].v, B1.v, zz, 0, 0, 0);
                    z[mt] = zz;
                }
                const int wloc = 8 * cc + k + 1;  // apply w_{tlo+i-1} to output rows
                float ov[4][4];
                #pragma unroll
                for (int mt = 0; mt < 4; ++mt) {
                    float4 wv = *(const float4*)(W16 + wloc * 64 + 16 * mt + 4 * q);
                    ov[mt][0] = z[mt][0] * wv.x;
                    ov[mt][1] = z[mt][1] * wv.y;
                    ov[mt][2] = z[mt][2] * wv.z;
                    ov[mt][3] = z[mt][3] * wv.w;
                }
                if (cc == 0 && k == 7) {          // single mid-chain rescale (i=9)
                    float mx = ov[0][0];
                    #pragma unroll
                    for (int mt = 0; mt < 4; ++mt)
                        #pragma unroll
                        for (int r = 0; r < 4; ++r) mx = fmaxf(mx, ov[mt][r]);
                    #pragma unroll
                    for (int off = 32; off; off >>= 1) mx = fmaxf(mx, __shfl_xor(mx, off));
                    lg += __logf(mx);
                    float rmx = 1.0f / mx;
                    #pragma unroll
                    for (int mt = 0; mt < 4; ++mt)
                        #pragma unroll
                        for (int r = 0; r < 4; ++r) ov[mt][r] *= rmx;
                }
                #pragma unroll
                for (int mt = 0; mt < 4; ++mt) {
                    int p0 = pack_bf16(ov[mt][0], ov[mt][1]);
                    int p1 = pack_bf16(ov[mt][2], ov[mt][3]);
                    *(uint2*)(QT + lcol * QPADB + 16 * mt + 4 * q) =
                        make_uint2((unsigned)p0, (unsigned)p1);
                }
            }
        }
    }

    // writeout: QT already holds P^T (w_last pre-applied) — straight copy
    unsigned short* qdst = wsQ + (size_t)(b * NSEG + s) * 4096 + (16 * g + lcol) * 64;
    #pragma unroll
    for (int u = 0; u < 2; ++u) {
        uint4 v = *(const uint4*)(QT + lcol * QPADB + 16 * q + 8 * u);
        *(uint4*)(qdst + 16 * q + 8 * u) = v;
    }
    if (lane == 0) wsS[(b * NSEG + s) * 4 + g] = lg;
}

// ---------------- Kernel 2: MFMA-based fold of a0 through active segments ----
__global__ __launch_bounds__(64) void crf_combine_kernel(
    const float* __restrict__ enc, const float* __restrict__ Tr,
    const int* __restrict__ lens,
    const unsigned short* __restrict__ wsQ, const float* __restrict__ wsS,
    float* __restrict__ out)
{
    const int b = blockIdx.x;
    const int j = threadIdx.x;
    const int len = lens[b];
    const int smax = (len - 2) / SEGLEN + 1;
    const int q = j >> 4;
    const int lcol = j & 15;

    const uint4* qb = (const uint4*)(wsQ + (size_t)b * NSEG * 4096);
    int fidx[4][2];
    #pragma unroll
    for (int mt = 0; mt < 4; ++mt)
        #pragma unroll
        for (int c2 = 0; c2 < 2; ++c2)
            fidx[mt][c2] = (16 * mt + lcol) * 8 + 4 * c2 + q;

    __shared__ __align__(16) float Al[64];

    float sc0 = wsS[b * (NSEG * 4) + j];
    float sc1 = wsS[b * (NSEG * 4) + 64 + j];

    float alpha0 = Tr[TSTART * LL + j] + enc[b * (SS * LL) + j];
    float m = alpha0;
    #pragma unroll
    for (int off = 32; off; off >>= 1) m = fmaxf(m, __shfl_xor(m, off));
    Al[j] = __expf(alpha0 - m);
    float logscale = m;
    float invmx = 1.0f;

    uint4 Abuf0[8], Abuf1[8];
    {
        const uint4* p1 = qb + (size_t)min(1, smax - 1) * 512;
        #pragma unroll
        for (int mt = 0; mt < 4; ++mt)
            #pragma unroll
            for (int c2 = 0; c2 < 2; ++c2) {
                Abuf0[mt * 2 + c2] = qb[fidx[mt][c2]];
                Abuf1[mt * 2 + c2] = p1[fidx[mt][c2]];
            }
    }

    int s = 0;
    auto fold = [&](uint4 (&cur)[8]) {
        float4 q0 = *(const float4*)(Al + 8 * q);
        float4 q1 = *(const float4*)(Al + 8 * q + 4);
        float4 q2 = *(const float4*)(Al + 32 + 8 * q);
        float4 q3 = *(const float4*)(Al + 32 + 8 * q + 4);
        S8 b0, b1;
        b0.i[0] = pack_bf16(q0.x * invmx, q0.y * invmx);
        b0.i[1] = pack_bf16(q0.z * invmx, q0.w * invmx);
        b0.i[2] = pack_bf16(q1.x * invmx, q1.y * invmx);
        b0.i[3] = pack_bf16(q1.z * invmx, q1.w * invmx);
        b1.i[0] = pack_bf16(q2.x * invmx, q2.y * invmx);
        b1.i[1] = pack_bf16(q2.z * invmx, q2.w * invmx);
        b1.i[2] = pack_bf16(q3.x * invmx, q3.y * invmx);
        b1.i[3] = pack_bf16(q3.z * invmx, q3.w * invmx);

        S8 a8[8];
        #pragma unroll
        for (int f = 0; f < 8; ++f) a8[f].u4 = cur[f];

        const uint4* pn = qb + (size_t)min(s + 2, smax - 1) * 512;
        #pragma unroll
        for (int mt = 0; mt < 4; ++mt)
            #pragma unroll
            for (int c2 = 0; c2 < 2; ++c2) cur[mt * 2 + c2] = pn[fidx[mt][c2]];

        floatx4 acc[4];
        #pragma unroll
        for (int mt = 0; mt < 4; ++mt) {
            floatx4 z = {0.f, 0.f, 0.f, 0.f};
            z = __builtin_amdgcn_mfma_f32_16x16x32_bf16(a8[2 * mt].v, b0.v, z, 0, 0, 0);
            z = __builtin_amdgcn_mfma_f32_16x16x32_bf16(a8[2 * mt + 1].v, b1.v, z, 0, 0, 0);
            acc[mt] = z;
        }

        float l0, l1, l2, l3;
        if (s < 16) {
            l0 = __shfl(sc0, 4 * s + 0); l1 = __shfl(sc0, 4 * s + 1);
            l2 = __shfl(sc0, 4 * s + 2); l3 = __shfl(sc0, 4 * s + 3);
        } else {
            int e = 4 * (s - 16);
            l0 = __shfl(sc1, e + 0); l1 = __shfl(sc1, e + 1);
            l2 = __shfl(sc1, e + 2); l3 = __shfl(sc1, e + 3);
        }
        float lmax = fmaxf(fmaxf(l0, l1), fmaxf(l2, l3));
        float e0 = __expf(l0 - lmax), e1 = __expf(l1 - lmax);
        float e2 = __expf(l2 - lmax), e3 = __expf(l3 - lmax);
        #pragma unroll
        for (int r = 0; r < 4; ++r) {
            acc[0][r] *= e0; acc[1][r] *= e1; acc[2][r] *= e2; acc[3][r] *= e3;
        }

        if (lcol == 0) {
            #pragma unroll
            for (int mt = 0; mt < 4; ++mt)
                *(float4*)(Al + 16 * mt + 4 * q) =
                    make_float4(acc[mt][0], acc[mt][1], acc[mt][2], acc[mt][3]);
        }

        float mx = acc[0][0];
        #pragma unroll
        for (int mt = 0; mt < 4; ++mt)
            #pragma unroll
            for (int r = 0; r < 4; ++r) mx = fmaxf(mx, acc[mt][r]);
        mx = fmaxf(mx, __shfl_xor(mx, 16));
        mx = fmaxf(mx, __shfl_xor(mx, 32));
        invmx = 1.0f / mx;
        logscale += lmax + __logf(mx);
    };

    while (s < smax) {
        fold(Abuf0);
        ++s;
        if (s >= smax) break;
        fold(Abuf1);
        ++s;
    }

    float aj = Al[j] * invmx;
    float f = aj * __expf(Tr[j * LL + TSTOP]);
    float ssum = f;
    #pragma unroll
    for (int off = 32; off; off >>= 1) ssum += __shfl_xor(ssum, off);
    if (j == 0) {
        const float LN2x7 = 7.0f * 0.69314718055994530942f;
        out[b] = logscale + (float)(len - 1) * LN2x7 + __logf(ssum);
    }
}

// ---------------- Fallback (exact, used if ws too small) ----------------
__global__ __launch_bounds__(256) void crf_kernel_fb(
    const float* __restrict__ enc, const float* __restrict__ Tr,
    const int* __restrict__ lens, const int* __restrict__ tags,
    float* __restrict__ out)
{
    if (blockIdx.x < BB) {
        const int tid = threadIdx.x;
        if (tid >= 64) return;
        const int b = blockIdx.x;
        const int j = tid;
        const int len = lens[b];
        const float* eb = enc + b * (SS * LL);
        float Ecol[LL];
        #pragma unroll
        for (int i = 0; i < LL; ++i) Ecol[i] = __expf(Tr[i * LL + j]) * 0.0078125f;
        float alpha0 = Tr[TSTART * LL + j] + eb[j];
        float m = alpha0;
        #pragma unroll
        for (int off = 32; off; off >>= 1) m = fmaxf(m, __shfl_xor(m, off));
        float a = __expf(alpha0 - m);
        float logscale = m;
        float ecur[4], enext[4];
        #pragma unroll
        for (int k = 0; k < 4; ++k) ecur[k] = eb[k * LL + j];
        #pragma unroll
        for (int k = 0; k < 4; ++k) enext[k] = eb[(4 + k) * LL + j];
        const int nchunk = (len + 3) >> 2;
        for (int c = 0; c < nchunk; ++c) {
            const int cpre = (c + 2 < 128) ? (c + 2) : 127;
            float efar[4];
            #pragma unroll
            for (int k = 0; k < 4; ++k) efar[k] = eb[(4 * cpre + k) * LL + j];
            #pragma unroll
            for (int k = 0; k < 4; ++k) {
                const int t = 4 * c + k;
                if (t >= 1 && t < len) {
                    const float w = __expf(ecur[k]);
                    const int ai = __float_as_int(a);
                    float s0 = 0.f, s1 = 0.f, s2 = 0.f, s3 = 0.f;
                    #pragma unroll
                    for (int qq = 0; qq < 16; ++qq) {
                        s0 = fmaf(__int_as_float(__builtin_amdgcn_readlane(ai, 4 * qq + 0)), Ecol[4 * qq + 0], s0);
                        s1 = fmaf(__int_as_float(__builtin_amdgcn_readlane(ai, 4 * qq + 1)), Ecol[4 * qq + 1], s1);
                        s2 = fmaf(__int_as_float(__builtin_amdgcn_readlane(ai, 4 * qq + 2)), Ecol[4 * qq + 2], s2);
                        s3 = fmaf(__int_as_float(__builtin_amdgcn_readlane(ai, 4 * qq + 3)), Ecol[4 * qq + 3], s3);
                    }
                    a = ((s0 + s1) + (s2 + s3)) * w;
                    if ((t & 7) == 7) {
                        float mm = a;
                        #pragma unroll
                        for (int off = 32; off; off >>= 1) mm = fmaxf(mm, __shfl_xor(mm, off));
                        logscale += __logf(mm);
                        a = a * (1.0f / mm);
                    }
                }
            }
            #pragma unroll
            for (int k = 0; k < 4; ++k) { ecur[k] = enext[k]; enext[k] = efar[k]; }
        }
        float f = a * __expf(Tr[j * LL + TSTOP]);
        float ssum = f;
        #pragma unroll
        for (int off = 32; off; off >>= 1) ssum += __shfl_xor(ssum, off);
        if (j == 0) {
            const float LN2x7 = 7.0f * 0.69314718055994530942f;
            out[b] = logscale + (float)(len - 1) * LN2x7 + __logf(ssum);
        }
    } else {
        const int b = blockIdx.x - BB;
        const int tid = threadIdx.x;
        const int len = lens[b];
        const int* tg = tags + b * SS;
        const float* eb = enc + b * (SS * LL);
        float acc = 0.f;
        for (int t = 1 + tid; t < len; t += 256) {
            int curt = tg[t], prevt = tg[t - 1];
            acc += Tr[prevt * LL + curt] + eb[t * LL + curt];
        }
        #pragma unroll
        for (int off = 32; off; off >>= 1) acc += __shfl_xor(acc, off);
        __shared__ float red[4];
        if ((tid & 63) == 0) red[tid >> 6] = acc;
        __syncthreads();
        if (tid == 0) {
            float tot = (red[0] + red[1]) + (red[2] + red[3]);
            int t0 = tg[0], te = tg[len - 1];
            tot += Tr[TSTART * LL + t0] + eb[t0];
            tot += Tr[te * LL + TSTOP];
            out[BB + b] = tot;
        }
    }
}

extern "C" void kernel_launch(void* const* d_in, const int* in_sizes, int n_in,
                              void* d_out, int out_size, void* d_ws, size_t ws_size,
                              hipStream_t stream) {
    const float* enc  = (const float*)d_in[0];
    const float* Tr   = (const float*)d_in[1];
    const int*   lens = (const int*)d_in[2];
    const int*   tags = (const int*)d_in[3];
    float* out = (float*)d_out;

    const size_t needQ = (size_t)BB * NSEG * 4096 * sizeof(unsigned short);  // 8 MB
    const size_t needS = (size_t)BB * NSEG * 4 * sizeof(float);              // 16 KB
    const size_t needA = (size_t)8 * 64 * sizeof(uint4);                     // 8 KB
    const size_t needE = (size_t)64 * 64 * sizeof(float);                    // 16 KB
    if (ws_size >= needQ + needS + needA + needE) {
        unsigned short* wsQ = (unsigned short*)d_ws;
        float* wsS = (float*)((char*)d_ws + needQ);
        uint4* tblA = (uint4*)((char*)d_ws + needQ + needS);
        float* tblE = (float*)((char*)d_ws + needQ + needS + needA);
        crf_prep_kernel<<<BB + 1, 64, 0, stream>>>(enc, Tr, lens, tags, tblA, tblE, out);
        crf_seg_kernel<<<BB * NSEG * 4, 64, 0, stream>>>(enc, lens, tblA, tblE, wsQ, wsS);
        crf_combine_kernel<<<BB, 64, 0, stream>>>(enc, Tr, lens, wsQ, wsS, out);
    } else {
        crf_kernel_fb<<<2 * BB, 256, 0, stream>>>(enc, Tr, lens, tags, out);
    }
}